// Round 13
// baseline (261.174 us; speedup 1.0000x reference)
//
#include <hip/hip_runtime.h>
#include <hip/hip_bf16.h>

typedef unsigned int uint;
typedef unsigned short ushort;
typedef short bf16x8 __attribute__((ext_vector_type(8)));
typedef ushort u16x8 __attribute__((ext_vector_type(8)));
typedef float f32x4 __attribute__((ext_vector_type(4)));

#define B_ 16
#define C_ 256
#define O_ 256
#define HW_ 4096
#define KK_ 2304   // 9 * 256, tap-major: k = tap*256 + c
#define HP_ 66     // halo-padded spatial dim

#define VMW(n) asm volatile("s_waitcnt vmcnt(" #n ")" ::: "memory")
#define SB0 __builtin_amdgcn_sched_barrier(0)

__device__ __forceinline__ ushort f2bf(float f) {
    uint u = __builtin_bit_cast(uint, f);
    uint r = (u + 0x7FFFu + ((u >> 16) & 1u)) >> 16;   // RNE
    return (ushort)r;
}

// ---------------- kernel 1: NCHW f32 -> padded NHWC bf16 + pool partials + halo ------
__global__ __launch_bounds__(256) void transpose_kernel(const float* __restrict__ x,
                                                        ushort* __restrict__ xT,
                                                        float* __restrict__ part) {
    __shared__ ushort tl[64][264];   // [w][c], pad 8 -> row stride 528B
    const int h = blockIdx.x, b = blockIdx.y;
    const int c = threadIdx.x;
    const float* src = x + (((size_t)(b * C_ + c)) * 64 + h) * 64;   // x[b][c][h][*]
    float s = 0.0f;
    #pragma unroll
    for (int j = 0; j < 16; ++j) {
        float4 v = ((const float4*)src)[j];
        s += v.x + v.y + v.z + v.w;
        tl[j * 4 + 0][c] = f2bf(v.x);
        tl[j * 4 + 1][c] = f2bf(v.y);
        tl[j * 4 + 2][c] = f2bf(v.z);
        tl[j * 4 + 3][c] = f2bf(v.w);
    }
    part[(b * C_ + c) * 64 + h] = s;
    // zero 5 halo pixels per block (260 total per sample, 64 blocks x 5 = 320 >= 260)
    ushort* xbs = xT + (size_t)b * HP_ * HP_ * C_;
    #pragma unroll
    for (int t = 0; t < 5; ++t) {
        int i = h * 5 + t;
        if (i < 260) {
            int hp, wp;
            if (i < 66)       { hp = 0;       wp = i;       }
            else if (i < 132) { hp = 65;      wp = i - 66;  }
            else if (i < 196) { hp = i - 131; wp = 0;       }
            else              { hp = i - 195; wp = 65;      }
            xbs[((size_t)hp * HP_ + wp) * C_ + c] = 0;
        }
    }
    __syncthreads();
    const int cw = threadIdx.x & 31, rw = threadIdx.x >> 5;
    ushort* dstrow = xT + (((size_t)(b * HP_) + h + 1) * HP_ + 1) * C_;  // xT[b][h+1][1][0]
    #pragma unroll
    for (int j = 0; j < 8; ++j) {
        int w = rw + 8 * j;
        *(u16x8*)(dstrow + (size_t)w * C_ + cw * 8) = *(const u16x8*)&tl[w][cw * 8];
    }
}

// ---------------- kernel 2: pooled reduce + gating softmax ----------------
__global__ __launch_bounds__(256) void gate_kernel(const float* __restrict__ part,
                                                   const float* __restrict__ gw,
                                                   float* __restrict__ gates) {
    const int b = blockIdx.x, c = threadIdx.x;
    const float4* pp = (const float4*)(part + (size_t)(b * C_ + c) * 64);
    float p = 0.0f;
    #pragma unroll
    for (int j = 0; j < 16; ++j) { float4 v = pp[j]; p += v.x + v.y + v.z + v.w; }
    p *= (1.0f / 4096.0f);
    float l0 = p * gw[0 * C_ + c], l1 = p * gw[1 * C_ + c];
    float l2 = p * gw[2 * C_ + c], l3 = p * gw[3 * C_ + c];
    #pragma unroll
    for (int off = 32; off; off >>= 1) {
        l0 += __shfl_down(l0, off); l1 += __shfl_down(l1, off);
        l2 += __shfl_down(l2, off); l3 += __shfl_down(l3, off);
    }
    __shared__ float red[4][4];
    const int wid = c >> 6, lane = c & 63;
    if (lane == 0) { red[wid][0] = l0; red[wid][1] = l1; red[wid][2] = l2; red[wid][3] = l3; }
    __syncthreads();
    if (c < 4) {
        float logit = red[0][c] + red[1][c] + red[2][c] + red[3][c];
        float m = logit;
        m = fmaxf(m, __shfl_xor(m, 1)); m = fmaxf(m, __shfl_xor(m, 2));
        float ex = expf(logit - m);
        float ssum = ex; ssum += __shfl_xor(ssum, 1); ssum += __shfl_xor(ssum, 2);
        gates[b * 4 + c] = ex / ssum;
    }
}

// ---------------- kernel 3: combine expert weights (tap-major k) ----------------
__global__ __launch_bounds__(256) void combine_kernel(const float* __restrict__ We,
                                                      const float* __restrict__ gates,
                                                      ushort* __restrict__ Wc) {
    const int o = blockIdx.x, c = threadIdx.x;
    __shared__ float g[64];
    if (c < 64) g[c] = gates[c];
    __syncthreads();
    float w[4][9];
    #pragma unroll
    for (int e = 0; e < 4; ++e) {
        const float* p = We + (((size_t)e * O_ + o) * C_ + c) * 9;
        #pragma unroll
        for (int tap = 0; tap < 9; ++tap) w[e][tap] = p[tap];
    }
    #pragma unroll
    for (int b = 0; b < B_; ++b) {
        float g0 = g[b*4+0], g1 = g[b*4+1], g2 = g[b*4+2], g3 = g[b*4+3];
        #pragma unroll
        for (int tap = 0; tap < 9; ++tap) {
            float v = g0*w[0][tap] + g1*w[1][tap] + g2*w[2][tap] + g3*w[3][tap];
            Wc[((size_t)(b * O_ + o)) * KK_ + tap * C_ + c] = f2bf(v);
        }
    }
}

// ---------------- kernel 4: 256x256 conv GEMM, ALL-DIRECT-TO-REG, zero barriers -----
// grid = 256 blocks (16 n-tiles x 16 samples) = 1/CU, 512 threads (8 waves, 2M x 4N).
// No LDS, no barriers: every wave independently streams its A (Wc) and B (xT NHWC)
// MFMA fragments straight into registers with plain global_load_dwordx4. 72 K-steps
// of 32; per step: 12 loads (8 A + 4 B) double-batched (A0/B0, A1/B1), counted
// VMW(12) -> each batch has TWO MFMA-phases (~1200 cyc) of latency cover since its
// loads issue right after the MFMA that frees the registers (WAR-safe, in-order
// issue). Redundant L2 traffic (A x4, B x2 across waves) ~192KB/step/CU < L2 BW.
// 8 independent waves/CU slip freely to hide each other's stalls (m114 mechanism).
__global__ __launch_bounds__(512, 2) void conv_kernel(const ushort* __restrict__ xT,
                                                      const ushort* __restrict__ Wc,
                                                      float* __restrict__ out) {
    // bijective XCD chunk swizzle: 32 consecutive wgids per XCD (2 samples/XCD)
    const int d = blockIdx.x;
    const int wgid = (d & 7) * 32 + (d >> 3);
    const int b  = wgid >> 4;
    const int n0 = (wgid & 15) * 256;

    const int tid = threadIdx.x;
    const int wid = tid >> 6, lane = tid & 63;
    const int lr = lane & 15, lg = lane >> 4;
    const int wro = (wid >> 2) * 128;           // wave M-offset (o)
    const int wco = (wid & 3) * 64;             // wave N-offset (px)

    const ushort* Wb = Wc + (size_t)(b * O_) * KK_;
    const ushort* xb = xT + (size_t)b * HP_ * HP_ * C_;

    // per-lane fragment offsets (elements)
    int aOff[8];
    #pragma unroll
    for (int m = 0; m < 8; ++m)
        aOff[m] = (wro + m * 16 + lr) * KK_ + lg * 8;
    const int hh = (n0 >> 6) + (wco >> 6);      // image row of this wave (uniform)
    int vB[4];
    #pragma unroll
    for (int nn = 0; nn < 4; ++nn)
        vB[nn] = ((hh + 1) * HP_ + (nn * 16 + lr + 1)) * C_ + lg * 8;

    f32x4 acc[8][4];
    #pragma unroll
    for (int i = 0; i < 8; ++i)
        #pragma unroll
        for (int j = 0; j < 4; ++j) acc[i][j] = (f32x4){0.f, 0.f, 0.f, 0.f};

    bf16x8 A0[8], B0[4], A1[8], B1[4];

    // K-step s (0..71): k-chunk = s*32; tap = s>>3, c-chunk = (s&7)*32
    auto issue = [&](bf16x8* A, bf16x8* Bv, int s) {
        const int tap = s >> 3, c0 = (s & 7) * 32;
        const int t3  = (tap * 11) >> 5;         // tap/3
        const int boff = ((t3 - 1) * HP_ + (tap - 3 * t3 - 1)) * C_ + c0;
        const ushort* aP = Wb + s * 32;
        #pragma unroll
        for (int m = 0; m < 8; ++m)
            A[m] = *(const bf16x8*)(aP + aOff[m]);
        #pragma unroll
        for (int nn = 0; nn < 4; ++nn)
            Bv[nn] = *(const bf16x8*)(xb + (boff + vB[nn]));
    };
    auto mfma32 = [&](bf16x8* A, bf16x8* Bv) {
        #pragma unroll
        for (int m = 0; m < 8; ++m)
            #pragma unroll
            for (int n = 0; n < 4; ++n)
                acc[m][n] = __builtin_amdgcn_mfma_f32_16x16x32_bf16(A[m], Bv[n], acc[m][n], 0, 0, 0);
    };

    issue(A0, B0, 0);
    issue(A1, B1, 1);

    #pragma unroll 1
    for (int s = 0; s < 70; s += 2) {
        VMW(12); SB0;                 // batch s landed; batch s+1 in flight
        mfma32(A0, B0);
        issue(A0, B0, s + 2);         // reuse regs freed by the MFMAs above
        VMW(12); SB0;                 // batch s+1 landed; batch s+2 in flight
        mfma32(A1, B1);
        issue(A1, B1, s + 3);
    }
    VMW(12); SB0;                     // batch 70 landed (71 in flight)
    mfma32(A0, B0);
    VMW(0); SB0;                      // batch 71 landed
    mfma32(A1, B1);

    // epilogue: C/D layout col=lane&15, row=(lane>>4)*4+j
    #pragma unroll
    for (int m = 0; m < 8; ++m)
        #pragma unroll
        for (int n = 0; n < 4; ++n)
            #pragma unroll
            for (int j = 0; j < 4; ++j) {
                int ro = wro + m * 16 + lg * 4 + j;
                int co = n0 + wco + n * 16 + lr;
                out[((size_t)(b * O_ + ro)) * HW_ + co] = acc[m][n][j];
            }
}

extern "C" void kernel_launch(void* const* d_in, const int* in_sizes, int n_in,
                              void* d_out, int out_size, void* d_ws, size_t ws_size,
                              hipStream_t stream) {
    const float* x  = (const float*)d_in[0];
    const float* We = (const float*)d_in[1];
    const float* gw = (const float*)d_in[2];
    float* out = (float*)d_out;

    // ws: part @0 (256KB), gates @262144, Wc @263168 (18.87MB -> 19137536),
    //     xT @19137536 (16*66*66*256*2B = 35.68MB) -> ~54.8MB total
    float*  part  = (float*)d_ws;
    float*  gates = (float*)((char*)d_ws + 262144);
    ushort* Wcomb = (ushort*)((char*)d_ws + 263168);
    ushort* xTp   = (ushort*)((char*)d_ws + 19137536);

    transpose_kernel<<<dim3(64, 16), 256, 0, stream>>>(x, xTp, part);
    gate_kernel<<<16, 256, 0, stream>>>(part, gw, gates);
    combine_kernel<<<O_, 256, 0, stream>>>(We, gates, Wcomb);
    conv_kernel<<<256, 512, 0, stream>>>(xTp, Wcomb, out);
}

// Round 14
// 124.053 us; speedup vs baseline: 2.1053x; 2.1053x over previous
//
#include <hip/hip_runtime.h>
#include <hip/hip_bf16.h>

typedef unsigned int uint;
typedef unsigned short ushort;
typedef short bf16x8 __attribute__((ext_vector_type(8)));
typedef ushort u16x8 __attribute__((ext_vector_type(8)));
typedef float f32x4 __attribute__((ext_vector_type(4)));

#define B_ 16
#define C_ 256
#define O_ 256
#define HW_ 4096
#define KK_ 2304   // 9 * 256, tap-major: k = tap*256 + c
#define HP_ 66     // halo-padded spatial dim

#define VMW(n) asm volatile("s_waitcnt vmcnt(" #n ")" ::: "memory")
#define LGW(n) asm volatile("s_waitcnt lgkmcnt(" #n ")" ::: "memory")
#define SB0 __builtin_amdgcn_sched_barrier(0)
#define PRIO1 __builtin_amdgcn_s_setprio(1)
#define PRIO0 __builtin_amdgcn_s_setprio(0)
#define BAR __builtin_amdgcn_s_barrier()

__device__ __forceinline__ ushort f2bf(float f) {
    uint u = __builtin_bit_cast(uint, f);
    uint r = (u + 0x7FFFu + ((u >> 16) & 1u)) >> 16;   // RNE
    return (ushort)r;
}

// async global->LDS, 16B per lane; LDS dest is wave-uniform base + lane*16
__device__ __forceinline__ void gl16(const ushort* g, ushort* l) {
    __builtin_amdgcn_global_load_lds(
        (const __attribute__((address_space(1))) void*)g,
        (__attribute__((address_space(3))) void*)l,
        16, 0, 0);
}

// ---------------- kernel 1: NCHW f32 -> padded NHWC bf16 + pool partials + halo ------
__global__ __launch_bounds__(256) void transpose_kernel(const float* __restrict__ x,
                                                        ushort* __restrict__ xT,
                                                        float* __restrict__ part) {
    __shared__ ushort tl[64][264];   // [w][c], pad 8 -> row stride 528B
    const int h = blockIdx.x, b = blockIdx.y;
    const int c = threadIdx.x;
    const float* src = x + (((size_t)(b * C_ + c)) * 64 + h) * 64;   // x[b][c][h][*]
    float s = 0.0f;
    #pragma unroll
    for (int j = 0; j < 16; ++j) {
        float4 v = ((const float4*)src)[j];
        s += v.x + v.y + v.z + v.w;
        tl[j * 4 + 0][c] = f2bf(v.x);
        tl[j * 4 + 1][c] = f2bf(v.y);
        tl[j * 4 + 2][c] = f2bf(v.z);
        tl[j * 4 + 3][c] = f2bf(v.w);
    }
    part[(b * C_ + c) * 64 + h] = s;
    // zero 5 halo pixels per block (260 total per sample, 64 blocks x 5 = 320 >= 260)
    ushort* xbs = xT + (size_t)b * HP_ * HP_ * C_;
    #pragma unroll
    for (int t = 0; t < 5; ++t) {
        int i = h * 5 + t;
        if (i < 260) {
            int hp, wp;
            if (i < 66)       { hp = 0;       wp = i;       }
            else if (i < 132) { hp = 65;      wp = i - 66;  }
            else if (i < 196) { hp = i - 131; wp = 0;       }
            else              { hp = i - 195; wp = 65;      }
            xbs[((size_t)hp * HP_ + wp) * C_ + c] = 0;
        }
    }
    __syncthreads();
    const int cw = threadIdx.x & 31, rw = threadIdx.x >> 5;
    ushort* dstrow = xT + (((size_t)(b * HP_) + h + 1) * HP_ + 1) * C_;  // xT[b][h+1][1][0]
    #pragma unroll
    for (int j = 0; j < 8; ++j) {
        int w = rw + 8 * j;
        *(u16x8*)(dstrow + (size_t)w * C_ + cw * 8) = *(const u16x8*)&tl[w][cw * 8];
    }
}

// ---------------- kernel 2: pooled reduce + gating softmax ----------------
__global__ __launch_bounds__(256) void gate_kernel(const float* __restrict__ part,
                                                   const float* __restrict__ gw,
                                                   float* __restrict__ gates) {
    const int b = blockIdx.x, c = threadIdx.x;
    const float4* pp = (const float4*)(part + (size_t)(b * C_ + c) * 64);
    float p = 0.0f;
    #pragma unroll
    for (int j = 0; j < 16; ++j) { float4 v = pp[j]; p += v.x + v.y + v.z + v.w; }
    p *= (1.0f / 4096.0f);
    float l0 = p * gw[0 * C_ + c], l1 = p * gw[1 * C_ + c];
    float l2 = p * gw[2 * C_ + c], l3 = p * gw[3 * C_ + c];
    #pragma unroll
    for (int off = 32; off; off >>= 1) {
        l0 += __shfl_down(l0, off); l1 += __shfl_down(l1, off);
        l2 += __shfl_down(l2, off); l3 += __shfl_down(l3, off);
    }
    __shared__ float red[4][4];
    const int wid = c >> 6, lane = c & 63;
    if (lane == 0) { red[wid][0] = l0; red[wid][1] = l1; red[wid][2] = l2; red[wid][3] = l3; }
    __syncthreads();
    if (c < 4) {
        float logit = red[0][c] + red[1][c] + red[2][c] + red[3][c];
        float m = logit;
        m = fmaxf(m, __shfl_xor(m, 1)); m = fmaxf(m, __shfl_xor(m, 2));
        float ex = expf(logit - m);
        float ssum = ex; ssum += __shfl_xor(ssum, 1); ssum += __shfl_xor(ssum, 2);
        gates[b * 4 + c] = ex / ssum;
    }
}

// ---------------- kernel 3: combine expert weights (tap-major k) ----------------
__global__ __launch_bounds__(256) void combine_kernel(const float* __restrict__ We,
                                                      const float* __restrict__ gates,
                                                      ushort* __restrict__ Wc) {
    const int o = blockIdx.x, c = threadIdx.x;
    __shared__ float g[64];
    if (c < 64) g[c] = gates[c];
    __syncthreads();
    float w[4][9];
    #pragma unroll
    for (int e = 0; e < 4; ++e) {
        const float* p = We + (((size_t)e * O_ + o) * C_ + c) * 9;
        #pragma unroll
        for (int tap = 0; tap < 9; ++tap) w[e][tap] = p[tap];
    }
    #pragma unroll
    for (int b = 0; b < B_; ++b) {
        float g0 = g[b*4+0], g1 = g[b*4+1], g2 = g[b*4+2], g3 = g[b*4+3];
        #pragma unroll
        for (int tap = 0; tap < 9; ++tap) {
            float v = g0*w[0][tap] + g1*w[1][tap] + g2*w[2][tap] + g3*w[3][tap];
            Wc[((size_t)(b * O_ + o)) * KK_ + tap * C_ + c] = f2bf(v);
        }
    }
}

// ---------------- kernel 4: 128x256 conv GEMM, TWO independent blocks per CU --------
// grid = 512 blocks (2 m x 16 n x 16 samples) = 2/CU, 256 threads (4 waves, 1M x 4N;
// wave tile 128x64). 72 K-tiles of BK=32, 3-slot LDS ring (72KB/block -> exactly 2
// blocks/CU). Per tile: stage 6 gl16 (t+2), read-ahead frags, LGW(4)/LGW(0) counted,
// ONE counted VMW(6) (stage t+2 stays in flight), ONE barrier. The second resident
// block fills this block's barrier/wait gaps (m114 inter-block overlap).
// 64B-row swizzle: granule ^= (row>>1)&3, source-side + read-side (2 lanes/bank).
__global__ __launch_bounds__(256, 2) void conv_kernel(const ushort* __restrict__ xT,
                                                      const ushort* __restrict__ Wc,
                                                      float* __restrict__ out) {
    __shared__ ushort As[3][128][32];   // [slot][o][k]   64B rows, linear DMA dest
    __shared__ ushort Bs[3][256][32];   // [slot][px][k]

    // bijective XCD chunk swizzle: 64 consecutive wgids per XCD (2 samples/XCD)
    const int d = blockIdx.x;
    const int wgid = (d & 7) * 64 + (d >> 3);
    const int b   = wgid >> 5;              // 32 blocks per sample
    const int mi  = (wgid >> 4) & 1;
    const int m0  = mi * 128;
    const int n0  = (wgid & 15) * 256;

    const int tid = threadIdx.x;
    const int wid = tid >> 6, lane = tid & 63;
    const int lr = lane & 15, lg = lane >> 4;
    const int wco = wid * 64;               // wave N-offset (px)

    // staging roles: granule swizzle by (row>>1)&3; row-in-chunk = lane>>2
    const int srow = lane >> 2;                       // 0..15
    const int sgr  = (lane & 3) ^ ((lane >> 3) & 3);  // source granule
    const ushort* aBase = Wc + ((size_t)(b * O_ + m0 + wid * 32 + srow)) * KK_ + sgr * 8;
    const ushort* xb = xT + (size_t)b * HP_ * HP_ * C_;
    const int hh = (n0 >> 6) + wid;                   // image row staged by this wave
    const ushort* bBase[4];
    #pragma unroll
    for (int i = 0; i < 4; ++i)
        bBase[i] = xb + ((size_t)(hh + 1) * HP_ + i * 16 + srow + 1) * C_ + sgr * 8;

    f32x4 acc[8][4];
    #pragma unroll
    for (int i = 0; i < 8; ++i)
        #pragma unroll
        for (int j = 0; j < 4; ++j) acc[i][j] = (f32x4){0.f, 0.f, 0.f, 0.f};

    auto stage = [&](int ss, int t) {
        const int tap = t >> 3, c0 = (t & 7) * 32;
        const int t3 = (tap * 11) >> 5;               // tap/3
        const int toff = ((t3 - 1) * HP_ + (tap - 3 * t3 - 1)) * C_ + c0;
        // A: 2 gl16 -> rows [wid*32, wid*32+32)
        gl16(aBase + (size_t)t * 32,            &As[ss][wid * 32][0]);
        gl16(aBase + (size_t)t * 32 + 16 * KK_, &As[ss][wid * 32 + 16][0]);
        // B: 4 gl16 -> pixel rows [wid*64, wid*64+64)
        #pragma unroll
        for (int i = 0; i < 4; ++i)
            gl16(bBase[i] + toff, &Bs[ss][wid * 64 + i * 16][0]);
    };

    bf16x8 aLo[4], aHi[4], bF[4];

    auto dsA = [&](int s, int h, bf16x8* dst) {
        #pragma unroll
        for (int m = 0; m < 4; ++m)
            dst[m] = *(const bf16x8*)
                &As[s][h * 64 + m * 16 + lr][(lg ^ ((lr >> 1) & 3)) * 8];
    };
    auto dsB = [&](int s, bf16x8* dst) {
        #pragma unroll
        for (int n = 0; n < 4; ++n)
            dst[n] = *(const bf16x8*)
                &Bs[s][wco + n * 16 + lr][(lg ^ ((lr >> 1) & 3)) * 8];
    };
    auto mfma16 = [&](int ao, bf16x8* a, bf16x8* bv) {
        #pragma unroll
        for (int m = 0; m < 4; ++m)
            #pragma unroll
            for (int n = 0; n < 4; ++n)
                acc[ao + m][n] = __builtin_amdgcn_mfma_f32_16x16x32_bf16(a[m], bv[n], acc[ao + m][n], 0, 0, 0);
    };

    // prologue: stage tiles 0,1; wait tile 0 (tile 1 in flight); pre-read tile 0
    stage(0, 0); stage(1, 1);
    VMW(6);
    BAR;
    dsA(0, 0, aLo); dsB(0, bF);      // 8 lgkm outstanding entering tile 0

    #pragma unroll 1
    for (int t = 0; t < 70; ++t) {
        const int s = t % 3, sn = (t + 1) % 3, ss = (t + 2) % 3;
        stage(ss, t + 2);                 // 6 gl16
        dsA(s, 1, aHi);                   // +4 lgkm (12 total)
        LGW(4); SB0;                      // pre-batch (aLo,bF) done; aHi may remain
        PRIO1; mfma16(0, aLo, bF); PRIO0;
        LGW(0); SB0;                      // aHi done
        PRIO1; mfma16(4, aHi, bF); PRIO0;
        VMW(6); SB0;                      // stage(t+1) landed; stage(t+2) in flight
        BAR;                              // cross-wave: slot sn ready, slot s drained
        dsA(sn, 0, aLo); dsB(sn, bF);     // pre-read next tile
    }
    // t=70 (slot 1): no stage; must drain stage(71) before reading slot 2
    {
        dsA(1, 1, aHi);
        LGW(4); SB0;
        PRIO1; mfma16(0, aLo, bF); PRIO0;
        LGW(0); SB0;
        PRIO1; mfma16(4, aHi, bF); PRIO0;
        VMW(0); SB0;
        BAR;
        dsA(2, 0, aLo); dsB(2, bF);
    }
    // t=71 (slot 2): final
    {
        dsA(2, 1, aHi);
        LGW(4); SB0;
        mfma16(0, aLo, bF);
        LGW(0); SB0;
        mfma16(4, aHi, bF);
    }

    // epilogue: C/D layout col=lane&15, row=(lane>>4)*4+j
    #pragma unroll
    for (int m = 0; m < 8; ++m)
        #pragma unroll
        for (int n = 0; n < 4; ++n)
            #pragma unroll
            for (int j = 0; j < 4; ++j) {
                int ro = m0 + m * 16 + lg * 4 + j;
                int co = n0 + wco + n * 16 + lr;
                out[((size_t)(b * O_ + ro)) * HW_ + co] = acc[m][n][j];
            }
}

extern "C" void kernel_launch(void* const* d_in, const int* in_sizes, int n_in,
                              void* d_out, int out_size, void* d_ws, size_t ws_size,
                              hipStream_t stream) {
    const float* x  = (const float*)d_in[0];
    const float* We = (const float*)d_in[1];
    const float* gw = (const float*)d_in[2];
    float* out = (float*)d_out;

    // ws: part @0 (256KB), gates @262144, Wc @263168 (18.87MB -> 19137536),
    //     xT @19137536 (16*66*66*256*2B = 35.68MB) -> ~54.8MB total
    float*  part  = (float*)d_ws;
    float*  gates = (float*)((char*)d_ws + 262144);
    ushort* Wcomb = (ushort*)((char*)d_ws + 263168);
    ushort* xTp   = (ushort*)((char*)d_ws + 19137536);

    transpose_kernel<<<dim3(64, 16), 256, 0, stream>>>(x, xTp, part);
    gate_kernel<<<16, 256, 0, stream>>>(part, gw, gates);
    combine_kernel<<<O_, 256, 0, stream>>>(We, gates, Wcomb);
    conv_kernel<<<512, 256, 0, stream>>>(xTp, Wcomb, out);
}

// Round 15
// 107.544 us; speedup vs baseline: 2.4285x; 1.1535x over previous
//
#include <hip/hip_runtime.h>
#include <hip/hip_bf16.h>

typedef unsigned int uint;
typedef unsigned short ushort;
typedef short bf16x8 __attribute__((ext_vector_type(8)));
typedef ushort u16x8 __attribute__((ext_vector_type(8)));
typedef float f32x4 __attribute__((ext_vector_type(4)));

#define B_ 16
#define C_ 256
#define O_ 256
#define HW_ 4096
#define KK_ 2304   // 9 * 256, tap-major: k = tap*256 + c
#define HP_ 66     // halo-padded spatial dim

#define VMW(n) asm volatile("s_waitcnt vmcnt(" #n ")" ::: "memory")
#define LGW(n) asm volatile("s_waitcnt lgkmcnt(" #n ")" ::: "memory")
#define SB0 __builtin_amdgcn_sched_barrier(0)
#define PRIO1 __builtin_amdgcn_s_setprio(1)
#define PRIO0 __builtin_amdgcn_s_setprio(0)
#define BAR __builtin_amdgcn_s_barrier()

__device__ __forceinline__ ushort f2bf(float f) {
    uint u = __builtin_bit_cast(uint, f);
    uint r = (u + 0x7FFFu + ((u >> 16) & 1u)) >> 16;   // RNE
    return (ushort)r;
}

// async global->LDS, 16B per lane; LDS dest is wave-uniform base + lane*16
__device__ __forceinline__ void gl16(const ushort* g, ushort* l) {
    __builtin_amdgcn_global_load_lds(
        (const __attribute__((address_space(1))) void*)g,
        (__attribute__((address_space(3))) void*)l,
        16, 0, 0);
}

// ---------------- kernel 1: NCHW f32 -> padded NHWC bf16 + pool partials + halo ------
__global__ __launch_bounds__(256) void transpose_kernel(const float* __restrict__ x,
                                                        ushort* __restrict__ xT,
                                                        float* __restrict__ part) {
    __shared__ ushort tl[64][264];   // [w][c], pad 8 -> row stride 528B
    const int h = blockIdx.x, b = blockIdx.y;
    const int c = threadIdx.x;
    const float* src = x + (((size_t)(b * C_ + c)) * 64 + h) * 64;   // x[b][c][h][*]
    float s = 0.0f;
    #pragma unroll
    for (int j = 0; j < 16; ++j) {
        float4 v = ((const float4*)src)[j];
        s += v.x + v.y + v.z + v.w;
        tl[j * 4 + 0][c] = f2bf(v.x);
        tl[j * 4 + 1][c] = f2bf(v.y);
        tl[j * 4 + 2][c] = f2bf(v.z);
        tl[j * 4 + 3][c] = f2bf(v.w);
    }
    part[(b * C_ + c) * 64 + h] = s;
    // zero 5 halo pixels per block (260 total per sample, 64 blocks x 5 = 320 >= 260)
    ushort* xbs = xT + (size_t)b * HP_ * HP_ * C_;
    #pragma unroll
    for (int t = 0; t < 5; ++t) {
        int i = h * 5 + t;
        if (i < 260) {
            int hp, wp;
            if (i < 66)       { hp = 0;       wp = i;       }
            else if (i < 132) { hp = 65;      wp = i - 66;  }
            else if (i < 196) { hp = i - 131; wp = 0;       }
            else              { hp = i - 195; wp = 65;      }
            xbs[((size_t)hp * HP_ + wp) * C_ + c] = 0;
        }
    }
    __syncthreads();
    const int cw = threadIdx.x & 31, rw = threadIdx.x >> 5;
    ushort* dstrow = xT + (((size_t)(b * HP_) + h + 1) * HP_ + 1) * C_;  // xT[b][h+1][1][0]
    #pragma unroll
    for (int j = 0; j < 8; ++j) {
        int w = rw + 8 * j;
        *(u16x8*)(dstrow + (size_t)w * C_ + cw * 8) = *(const u16x8*)&tl[w][cw * 8];
    }
}

// ---------------- kernel 2: pooled reduce + gating softmax ----------------
__global__ __launch_bounds__(256) void gate_kernel(const float* __restrict__ part,
                                                   const float* __restrict__ gw,
                                                   float* __restrict__ gates) {
    const int b = blockIdx.x, c = threadIdx.x;
    const float4* pp = (const float4*)(part + (size_t)(b * C_ + c) * 64);
    float p = 0.0f;
    #pragma unroll
    for (int j = 0; j < 16; ++j) { float4 v = pp[j]; p += v.x + v.y + v.z + v.w; }
    p *= (1.0f / 4096.0f);
    float l0 = p * gw[0 * C_ + c], l1 = p * gw[1 * C_ + c];
    float l2 = p * gw[2 * C_ + c], l3 = p * gw[3 * C_ + c];
    #pragma unroll
    for (int off = 32; off; off >>= 1) {
        l0 += __shfl_down(l0, off); l1 += __shfl_down(l1, off);
        l2 += __shfl_down(l2, off); l3 += __shfl_down(l3, off);
    }
    __shared__ float red[4][4];
    const int wid = c >> 6, lane = c & 63;
    if (lane == 0) { red[wid][0] = l0; red[wid][1] = l1; red[wid][2] = l2; red[wid][3] = l3; }
    __syncthreads();
    if (c < 4) {
        float logit = red[0][c] + red[1][c] + red[2][c] + red[3][c];
        float m = logit;
        m = fmaxf(m, __shfl_xor(m, 1)); m = fmaxf(m, __shfl_xor(m, 2));
        float ex = expf(logit - m);
        float ssum = ex; ssum += __shfl_xor(ssum, 1); ssum += __shfl_xor(ssum, 2);
        gates[b * 4 + c] = ex / ssum;
    }
}

// ---------------- kernel 3: combine expert weights (tap-major k) ----------------
__global__ __launch_bounds__(256) void combine_kernel(const float* __restrict__ We,
                                                      const float* __restrict__ gates,
                                                      ushort* __restrict__ Wc) {
    const int o = blockIdx.x, c = threadIdx.x;
    __shared__ float g[64];
    if (c < 64) g[c] = gates[c];
    __syncthreads();
    float w[4][9];
    #pragma unroll
    for (int e = 0; e < 4; ++e) {
        const float* p = We + (((size_t)e * O_ + o) * C_ + c) * 9;
        #pragma unroll
        for (int tap = 0; tap < 9; ++tap) w[e][tap] = p[tap];
    }
    #pragma unroll
    for (int b = 0; b < B_; ++b) {
        float g0 = g[b*4+0], g1 = g[b*4+1], g2 = g[b*4+2], g3 = g[b*4+3];
        #pragma unroll
        for (int tap = 0; tap < 9; ++tap) {
            float v = g0*w[0][tap] + g1*w[1][tap] + g2*w[2][tap] + g3*w[3][tap];
            Wc[((size_t)(b * O_ + o)) * KK_ + tap * C_ + c] = f2bf(v);
        }
    }
}

// ---------------- kernel 4: 256x256 conv GEMM — faithful m201 4-phase schedule ------
// grid = 256 blocks = 1/CU, 512 threads (8 waves, 2M x 4N; wave 128x64). 36 K-tiles
// of BK=64, 2 dbuf (128KB), R7's 0-conflict 128B-row XOR swizzle.
// Per tile 4 phases: {ds-reads (12/4/8/0) | 2-gl16 stage -> BAR -> LGW(0)+SB0 ->
// prio1 16 MFMA prio0 -> [VMW(2) at P0,P3 only] -> BAR}. Reads consumed same-phase;
// A-frags register-reused across n-halves; stage order (A0,A1,B0,B1) matches
// consumption so counted VMW(2) suffices (never 0 mid-loop). Every cross-wave
// DMA->read pair is separated by a VMW-then-BAR.
__global__ __launch_bounds__(512, 2) void conv_kernel(const ushort* __restrict__ xT,
                                                      const ushort* __restrict__ Wc,
                                                      float* __restrict__ out) {
    __shared__ ushort As[2][256][64];   // [dbuf][o][k]  128B rows, linear DMA dest
    __shared__ ushort Bs[2][256][64];   // [dbuf][px][k]

    // bijective XCD chunk swizzle: 32 consecutive wgids per XCD (2 samples/XCD)
    const int d0 = blockIdx.x;
    const int wgid = (d0 & 7) * 32 + (d0 >> 3);
    const int b  = wgid >> 4;
    const int n0 = (wgid & 15) * 256;

    const int tid = threadIdx.x;
    const int wid = tid >> 6, lane = tid & 63;
    const int lr = lane & 15, lg = lane >> 4;
    const int wro = (wid >> 2) * 128;           // wave M-offset (o)
    const int wco = (wid & 3) * 64;             // wave N-offset (px)

    // staging lane roles (R7 swizzle: row = lane>>3, granule = (lane&7)^row)
    const int srow = lane >> 3;                 // 0..7
    const int sgr  = (lane & 7) ^ srow;
    // A: phase-half 'ah' stages rows rA(ah) = (wid>>2)*128 + (wid&3)*16 + ah*64, 2 gl16 (8 rows each)
    const int rA = (wid >> 2) * 128 + (wid & 3) * 16;
    const ushort* aSb = Wc + ((size_t)(b * O_ + rA + srow)) * KK_ + sgr * 8;
    // B: phase-half 'bh' stages px pB(bh) = (wid&3)*64 + (wid>>2)*16 + bh*32 (within one 64-px row)
    const ushort* xb = xT + (size_t)b * HP_ * HP_ * C_;
    const int hh  = (n0 >> 6) + (wid & 3);      // image row staged by this wave (uniform)
    const int pW  = (wid >> 2) * 16;            // px offset within row-half
    const ushort* bSb = xb + ((size_t)(hh + 1) * HP_ + pW + srow + 1) * C_ + sgr * 8;

    f32x4 acc[8][4];
    #pragma unroll
    for (int i = 0; i < 8; ++i)
        #pragma unroll
        for (int j = 0; j < 4; ++j) acc[i][j] = (f32x4){0.f, 0.f, 0.f, 0.f};

    auto stageA = [&](int dn, int t, int ah) {
        #pragma unroll
        for (int i = 0; i < 2; ++i)
            gl16(aSb + (size_t)(ah * 64 + i * 8) * KK_ + t * 64,
                 &As[dn][rA + ah * 64 + i * 8][0]);
    };
    auto stageB = [&](int dn, int t, int bh) {
        const int tap = t >> 2, c0 = (t & 3) * 64;
        const int t3 = (tap * 11) >> 5;          // tap/3
        const int toff = ((t3 - 1) * HP_ + (tap - 3 * t3 - 1)) * C_ + c0;
        #pragma unroll
        for (int i = 0; i < 2; ++i)
            gl16(bSb + (size_t)(bh * 32 + i * 8) * C_ + toff,
                 &Bs[dn][wco + pW + bh * 32 + i * 8][0]);
    };

    bf16x8 aF[4][2], bF0[2][2], bF1[2][2];

    auto rdA = [&](int dd, int mh, bf16x8 dst[4][2]) {
        #pragma unroll
        for (int m = 0; m < 4; ++m)
            #pragma unroll
            for (int k = 0; k < 2; ++k)
                dst[m][k] = *(const bf16x8*)
                    &As[dd][wro + mh * 64 + m * 16 + lr][(((k << 2) | lg) ^ (lr & 7)) * 8];
    };
    auto rdB = [&](int dd, int nh, bf16x8 dst[2][2]) {
        #pragma unroll
        for (int n = 0; n < 2; ++n)
            #pragma unroll
            for (int k = 0; k < 2; ++k)
                dst[n][k] = *(const bf16x8*)
                    &Bs[dd][wco + nh * 32 + n * 16 + lr][(((k << 2) | lg) ^ (lr & 7)) * 8];
    };
    auto mfmaQ = [&](int m0, int n0q, bf16x8 a[4][2], bf16x8 bv[2][2]) {
        #pragma unroll
        for (int m = 0; m < 4; ++m)
            #pragma unroll
            for (int n = 0; n < 2; ++n)
                #pragma unroll
                for (int k = 0; k < 2; ++k)
                    acc[m0 + m][n0q + n] =
                        __builtin_amdgcn_mfma_f32_16x16x32_bf16(a[m][k], bv[n][k], acc[m0 + m][n0q + n], 0, 0, 0);
    };

    // prologue: stage tile 0 fully into dbuf 0 (order A0,A1,B0,B1); VMW(2)+BAR
    stageA(0, 0, 0); stageA(0, 0, 1); stageB(0, 0, 0); stageB(0, 0, 1);
    VMW(2);                    // A0,A1,B0 landed; B1 (last pair) still in flight
    BAR;

    #pragma unroll 1
    for (int t = 0; t < 35; ++t) {
        const int dd = t & 1, dn = dd ^ 1;
        // P0: reads A(mh0)+B(nh0); stage A-half0(t+1); VMW(2) drains prev B1 at end
        rdA(dd, 0, aF); rdB(dd, 0, bF0);
        stageA(dn, t + 1, 0);
        BAR;
        LGW(0); SB0;
        PRIO1; mfmaQ(0, 0, aF, bF0); PRIO0;
        VMW(2);                // prev tile's B1 landed; own A-half0 in flight
        BAR;
        // P1: reads B(nh1); stage A-half1(t+1)
        rdB(dd, 1, bF1);
        stageA(dn, t + 1, 1);
        BAR;
        LGW(0); SB0;
        PRIO1; mfmaQ(0, 2, aF, bF1); PRIO0;
        BAR;
        // P2: reads A(mh1); stage B-half0(t+1)
        rdA(dd, 1, aF);
        stageB(dn, t + 1, 0);
        BAR;
        LGW(0); SB0;
        PRIO1; mfmaQ(4, 2, aF, bF1); PRIO0;
        BAR;
        // P3: no reads; stage B-half1(t+1); VMW(2) leaves only B1(t+1) in flight
        stageB(dn, t + 1, 1);
        BAR;
        PRIO1; mfmaQ(4, 0, aF, bF0); PRIO0;
        VMW(2);                // A0',A1',B0' of t+1 landed; B1' in flight
        BAR;
    }
    // tile 35 (dbuf 1), no staging
    {
        rdA(1, 0, aF); rdB(1, 0, bF0);
        BAR;
        LGW(0); SB0;
        PRIO1; mfmaQ(0, 0, aF, bF0); PRIO0;
        VMW(0);                // drain tile-34's B1
        BAR;
        rdB(1, 1, bF1);
        BAR;
        LGW(0); SB0;
        PRIO1; mfmaQ(0, 2, aF, bF1); PRIO0;
        BAR;
        rdA(1, 1, aF);
        BAR;
        LGW(0); SB0;
        PRIO1; mfmaQ(4, 2, aF, bF1); PRIO0;
        BAR;
        PRIO1; mfmaQ(4, 0, aF, bF0); PRIO0;
    }

    // epilogue: C/D layout col=lane&15, row=(lane>>4)*4+j
    #pragma unroll
    for (int m = 0; m < 8; ++m)
        #pragma unroll
        for (int n = 0; n < 4; ++n)
            #pragma unroll
            for (int j = 0; j < 4; ++j) {
                int ro = wro + m * 16 + lg * 4 + j;
                int co = n0 + wco + n * 16 + lr;
                out[((size_t)(b * O_ + ro)) * HW_ + co] = acc[m][n][j];
            }
}

extern "C" void kernel_launch(void* const* d_in, const int* in_sizes, int n_in,
                              void* d_out, int out_size, void* d_ws, size_t ws_size,
                              hipStream_t stream) {
    const float* x  = (const float*)d_in[0];
    const float* We = (const float*)d_in[1];
    const float* gw = (const float*)d_in[2];
    float* out = (float*)d_out;

    // ws: part @0 (256KB), gates @262144, Wc @263168 (18.87MB -> 19137536),
    //     xT @19137536 (16*66*66*256*2B = 35.68MB) -> ~54.8MB total
    float*  part  = (float*)d_ws;
    float*  gates = (float*)((char*)d_ws + 262144);
    ushort* Wcomb = (ushort*)((char*)d_ws + 263168);
    ushort* xTp   = (ushort*)((char*)d_ws + 19137536);

    transpose_kernel<<<dim3(64, 16), 256, 0, stream>>>(x, xTp, part);
    gate_kernel<<<16, 256, 0, stream>>>(part, gw, gates);
    combine_kernel<<<O_, 256, 0, stream>>>(We, gates, Wcomb);
    conv_kernel<<<256, 512, 0, stream>>>(xTp, Wcomb, out);
}